// Round 11
// baseline (252.889 us; speedup 1.0000x reference)
//
#include <hip/hip_runtime.h>
#include <math.h>

constexpr int B_ = 8, C_ = 1280, H_ = 7, W_ = 7;
constexpr int M_ = 2048, N_ = 128, HID = 256, NC = 21;
constexpr int DET_OFF = M_ * NC;          // 43008
constexpr int IOU_OFF = M_ * NC + M_ * 4; // 51200
constexpr int NRECT = 784;                // 28 y-intervals x 28 x-intervals
constexpr int GRID = 256;

typedef __attribute__((ext_vector_type(8))) short bf16x8;
typedef __attribute__((ext_vector_type(8))) unsigned short u16x8;
typedef __attribute__((ext_vector_type(4))) float f32x4;

// ws layout (bytes)
constexpr size_t W1T_OFF = 0;                    // 1280*256*2 = 655360
constexpr size_t W2T_OFF = W1T_OFF + 655360;     // 256*256*2  = 131072
constexpr size_t WHT_OFF = W2T_OFF + 131072;     // 32*256*2   =  16384
constexpr size_t AM_OFF  = WHT_OFF + 16384;      // 8*784*1280*2 = 16056320
constexpr size_t CNT_OFF = AM_OFF + 16056320;    // 64B aligned counter

struct KParams {
    const float *fmap, *props, *bbx, *W1, *b1v, *W2, *b2v, *Wc, *bc, *Wd, *bd;
    const int *pbid, *gbid;
    float *out;
    unsigned short *W1t, *W2t, *Wht, *allmax;
    unsigned *cnt;
};

__device__ __forceinline__ unsigned short f2bf(float f) {
    unsigned u = __builtin_bit_cast(unsigned, f);
    u += 0x7FFFu + ((u >> 16) & 1u);   // round-to-nearest-even
    return (unsigned short)(u >> 16);
}
__device__ __forceinline__ float bf2f(unsigned short u) {
    return __builtin_bit_cast(float, (unsigned)u << 16);
}
// interval index for 0 <= s < e <= 7  ->  [0,28)
__device__ __forceinline__ int ivix(int s, int e) {
    return s * 7 - ((s * (s - 1)) >> 1) + (e - s - 1);
}

// phase0: 160 rect units (img, 64ch) + 40 W1 + 8 W2 + 1 WH = 209 units over 256 blocks
__global__ __launch_bounds__(1024) void k_all(KParams P)
{
    __shared__ __align__(16) unsigned char smem[8 * 1288 * 2];  // tile (12.5KB) / featL (20.6KB)
    __shared__ unsigned short h1s[16][264];
    __shared__ unsigned short h2s[16][264];
    __shared__ float gbox[N_][4];
    __shared__ int   gids[N_];

    float* tile = (float*)smem;                          // [64][49]
    auto featL = (unsigned short (*)[1288])smem;         // [8][1288]

    const int tid = threadIdx.x;
    const int b   = blockIdx.x;

    if (tid < N_) {
        gbox[tid][0] = P.bbx[tid * 5 + 0];
        gbox[tid][1] = P.bbx[tid * 5 + 1];
        gbox[tid][2] = P.bbx[tid * 5 + 2];
        gbox[tid][3] = P.bbx[tid * 5 + 3];
        gids[tid] = P.gbid[tid];
    }

    // ---------------- phase 0 ----------------
    if (b < 160) {
        // rect-max for (img, 64-ch tile), direct coalesced global stores
        int img = b / 20, c0 = (b % 20) * 64;
        const float* src = P.fmap + ((size_t)img * C_ + c0) * 49;
        for (int i4 = tid; i4 < 784; i4 += 1024)
            *(float4*)&tile[i4 * 4] = *(const float4*)(src + i4 * 4);
        __syncthreads();

        if (tid < 448) {                       // wave = one sy (uniform), lane = channel
            int c = tid & 63, sy = tid >> 6;   // sy in [0,7)
            const float* tc = tile + c * 49;
            unsigned short* dst = P.allmax + (size_t)img * NRECT * C_ + c0 + c;
            float colacc[7];
            #pragma unroll
            for (int x = 0; x < 7; ++x) colacc[x] = -INFINITY;
            for (int ey = sy + 1; ey <= 7; ++ey) {
                int y = ey - 1;
                #pragma unroll
                for (int x = 0; x < 7; ++x)
                    colacc[x] = fmaxf(colacc[x], tc[y * 7 + x]);
                int yi = ivix(sy, ey);
                int xi = 0;
                #pragma unroll
                for (int sx = 0; sx < 7; ++sx) {
                    float mx = -INFINITY;
                    #pragma unroll
                    for (int ex = sx + 1; ex <= 7; ++ex) {
                        mx = fmaxf(mx, colacc[ex - 1]);
                        dst[(size_t)(yi * 28 + xi) * C_] = f2bf(mx);
                        ++xi;
                    }
                }
            }
        }
    } else if (b < 200) {
        int u = b - 160;                       // W1^T: 32 k-rows per unit
        int col = tid & 255, kj = tid >> 8;
        int k0 = u * 32 + kj * 8;
        u16x8 o;
        #pragma unroll
        for (int j = 0; j < 8; ++j) o[j] = f2bf(P.W1[(size_t)(k0 + j) * HID + col]);
        *(u16x8*)(P.W1t + (size_t)col * C_ + k0) = o;
    } else if (b < 208) {
        int u = b - 200;                       // W2^T
        int col = tid & 255, kj = tid >> 8;
        int k0 = u * 32 + kj * 8;
        u16x8 o;
        #pragma unroll
        for (int j = 0; j < 8; ++j) o[j] = f2bf(P.W2[(size_t)(k0 + j) * HID + col]);
        *(u16x8*)(P.W2t + (size_t)col * HID + k0) = o;
    } else if (b == 208) {
        int o32 = tid & 31;                    // Whead^T (32 cols padded)
        int k0  = (tid >> 5) * 8;
        u16x8 o;
        #pragma unroll
        for (int j = 0; j < 8; ++j) {
            float v = 0.0f;
            if (o32 < NC) v = P.Wc[(size_t)(k0 + j) * NC + o32];
            else if (o32 < NC + 4) v = P.Wd[(size_t)(k0 + j) * 4 + (o32 - NC)];
            o[j] = f2bf(v);
        }
        *(u16x8*)(P.Wht + (size_t)o32 * HID + k0) = o;
    }

    // ---- hand-rolled device barrier (all 256 blocks co-resident: 1 block/CU) ----
    __threadfence();                 // release: drain stores device-wide
    __syncthreads();
    if (tid == 0) {
        __hip_atomic_fetch_add(P.cnt, 1u, __ATOMIC_ACQ_REL, __HIP_MEMORY_SCOPE_AGENT);
        while (__hip_atomic_load(P.cnt, __ATOMIC_ACQUIRE, __HIP_MEMORY_SCOPE_AGENT) < (unsigned)GRID)
            __builtin_amdgcn_s_sleep(8);
    }
    __syncthreads();
    __threadfence();                 // acquire: invalidate before reading remote data

    // ---------------- per-block FC pipeline (8 proposals) ----------------
    const int row0 = b * 8;

    if (tid < 512) {   // gather-pool: wave = proposal
        int p = tid >> 6, lane = tid & 63;
        int m = row0 + p;
        float4 bx = *(const float4*)(P.props + (size_t)m * 4);
        float x1 = rintf(bx.x), y1 = rintf(bx.y);
        float x2 = rintf(bx.z), y2 = rintf(bx.w);
        float rw = fmaxf(x2 - x1 + 1.0f, 1.0f);
        float rh = fmaxf(y2 - y1 + 1.0f, 1.0f);
        float bw = rw * 0.5f, bh = rh * 0.5f;
        int hs0 = __builtin_amdgcn_readfirstlane((int)fminf(fmaxf(y1, 0.f), 7.f));
        int he0 = __builtin_amdgcn_readfirstlane((int)fminf(fmaxf(ceilf(bh) + y1, 0.f), 7.f));
        int hs1 = __builtin_amdgcn_readfirstlane((int)fminf(fmaxf(floorf(bh) + y1, 0.f), 7.f));
        int he1 = __builtin_amdgcn_readfirstlane((int)fminf(fmaxf(ceilf(2.f * bh) + y1, 0.f), 7.f));
        int ws0 = __builtin_amdgcn_readfirstlane((int)fminf(fmaxf(x1, 0.f), 7.f));
        int we0 = __builtin_amdgcn_readfirstlane((int)fminf(fmaxf(ceilf(bw) + x1, 0.f), 7.f));
        int ws1 = __builtin_amdgcn_readfirstlane((int)fminf(fmaxf(floorf(bw) + x1, 0.f), 7.f));
        int we1 = __builtin_amdgcn_readfirstlane((int)fminf(fmaxf(ceilf(2.f * bw) + x1, 0.f), 7.f));
        int bid = __builtin_amdgcn_readfirstlane(P.pbid[m]);

        int v00 = (he0 > hs0) & (we0 > ws0);
        int v01 = (he0 > hs0) & (we1 > ws1);
        int v10 = (he1 > hs1) & (we0 > ws0);
        int v11 = (he1 > hs1) & (we1 > ws1);
        int yi0 = v00 | v01 ? ivix(hs0, max(he0, hs0 + 1)) : 0;
        int yi1 = v10 | v11 ? ivix(hs1, max(he1, hs1 + 1)) : 0;
        int xi0 = v00 | v10 ? ivix(ws0, max(we0, ws0 + 1)) : 0;
        int xi1 = v01 | v11 ? ivix(ws1, max(we1, ws1 + 1)) : 0;
        const unsigned short* base = P.allmax + (size_t)bid * NRECT * C_;
        const unsigned short* a00 = base + (size_t)(yi0 * 28 + xi0) * C_;
        const unsigned short* a01 = base + (size_t)(yi0 * 28 + xi1) * C_;
        const unsigned short* a10 = base + (size_t)(yi1 * 28 + xi0) * C_;
        const unsigned short* a11 = base + (size_t)(yi1 * 28 + xi1) * C_;
        float m00 = v00 ? 0.25f : 0.0f;
        float m01 = v01 ? 0.25f : 0.0f;
        float m10 = v10 ? 0.25f : 0.0f;
        float m11 = v11 ? 0.25f : 0.0f;

        #pragma unroll
        for (int it = 0; it < 5; ++it) {
            int c = it * 256 + lane * 4;
            ushort4 u0 = *(const ushort4*)(a00 + c);
            ushort4 u1 = *(const ushort4*)(a01 + c);
            ushort4 u2 = *(const ushort4*)(a10 + c);
            ushort4 u3 = *(const ushort4*)(a11 + c);
            ushort4 o;
            o.x = f2bf(bf2f(u0.x) * m00 + bf2f(u1.x) * m01 + bf2f(u2.x) * m10 + bf2f(u3.x) * m11);
            o.y = f2bf(bf2f(u0.y) * m00 + bf2f(u1.y) * m01 + bf2f(u2.y) * m10 + bf2f(u3.y) * m11);
            o.z = f2bf(bf2f(u0.z) * m00 + bf2f(u1.z) * m01 + bf2f(u2.z) * m10 + bf2f(u3.z) * m11);
            o.w = f2bf(bf2f(u0.w) * m00 + bf2f(u1.w) * m01 + bf2f(u2.w) * m10 + bf2f(u3.w) * m11);
            *(ushort4*)&featL[p][c] = o;
        }
    }
    __syncthreads();

    const int w = tid >> 6, lane = tid & 63;
    const int r = lane & 15, g = lane >> 4;
    const int col0 = w * 16;   // wave covers 16 cols

    // ---- FC1: A from LDS, B depth-2 prefetch ----
    f32x4 acc = (f32x4){0.f, 0.f, 0.f, 0.f};
    const unsigned short* arp = featL[r & 7] + g * 8;
    const unsigned short* bp  = P.W1t + (size_t)(col0 + r) * C_ + g * 8;

    bf16x8 aA = *(const bf16x8*)arp;
    bf16x8 bA = *(const bf16x8*)bp;
    bf16x8 aB = *(const bf16x8*)(arp + 32);
    bf16x8 bB = *(const bf16x8*)(bp + 32);
    for (int ks = 2; ks < 40; ++ks) {
        bf16x8 aN = *(const bf16x8*)(arp + ks * 32);
        bf16x8 bN = *(const bf16x8*)(bp  + ks * 32);
        acc = __builtin_amdgcn_mfma_f32_16x16x32_bf16(aA, bA, acc, 0, 0, 0);
        aA = aB; bA = bB; aB = aN; bB = bN;
    }
    acc = __builtin_amdgcn_mfma_f32_16x16x32_bf16(aA, bA, acc, 0, 0, 0);
    acc = __builtin_amdgcn_mfma_f32_16x16x32_bf16(aB, bB, acc, 0, 0, 0);

    {
        int col = col0 + r;
        float bias = P.b1v[col];
        #pragma unroll
        for (int i = 0; i < 4; ++i)
            h1s[g * 4 + i][col] = f2bf(fmaxf(acc[i] + bias, 0.f));
    }

    // FC2 B preload (independent of h1s) before the barrier
    const unsigned short* bq = P.W2t + (size_t)(col0 + r) * HID + g * 8;
    bf16x8 u[8];
    #pragma unroll
    for (int ks = 0; ks < 8; ++ks) u[ks] = *(const bf16x8*)(bq + ks * 32);

    __syncthreads();

    // ---- FC2 ----
    f32x4 c2 = (f32x4){0.f, 0.f, 0.f, 0.f};
    #pragma unroll
    for (int ks = 0; ks < 8; ++ks) {
        bf16x8 a = *(const bf16x8*)(&h1s[r][ks * 32 + g * 8]);
        c2 = __builtin_amdgcn_mfma_f32_16x16x32_bf16(a, u[ks], c2, 0, 0, 0);
    }
    {
        int col = col0 + r;
        float bias = P.b2v[col];
        #pragma unroll
        for (int i = 0; i < 4; ++i)
            h2s[g * 4 + i][col] = f2bf(c2[i] + bias);
    }
    __syncthreads();

    // ---- heads on wave 0 (rows 0..7 valid) ----
    if (w == 0) {
        f32x4 acc3[2];
        #pragma unroll
        for (int f = 0; f < 2; ++f) acc3[f] = (f32x4){0.f, 0.f, 0.f, 0.f};
        const unsigned short* bp3 = P.Wht + (size_t)r * HID + g * 8;
        #pragma unroll
        for (int ks = 0; ks < 8; ++ks) {
            bf16x8 a = *(const bf16x8*)(&h2s[r][ks * 32 + g * 8]);
            #pragma unroll
            for (int f = 0; f < 2; ++f) {
                bf16x8 bb = *(const bf16x8*)(bp3 + (size_t)f * 16 * HID + ks * 32);
                acc3[f] = __builtin_amdgcn_mfma_f32_16x16x32_bf16(a, bb, acc3[f], 0, 0, 0);
            }
        }
        if (g < 2) {
            #pragma unroll
            for (int f = 0; f < 2; ++f) {
                int col = f * 16 + r;
                #pragma unroll
                for (int i = 0; i < 4; ++i) {
                    int m = row0 + g * 4 + i;
                    if (col < NC)
                        P.out[(size_t)m * NC + col] = acc3[f][i] + P.bc[col];
                    else if (col < NC + 4)
                        P.out[DET_OFF + (size_t)m * 4 + (col - NC)] = acc3[f][i] + P.bd[col - NC];
                }
            }
        }
    }

    // ---- IoU: waves 0..7 ----
    if (w < 8) {
        int m = row0 + w;
        float4 bxp = *(const float4*)(P.props + (size_t)m * 4);
        float ap2 = (bxp.z - bxp.x) * (bxp.w - bxp.y);
        int pb = P.pbid[m];
        float best = 0.0f;
        for (int n = lane; n < N_; n += 64) {
            if (gids[n] == pb) {
                float ix = fmaxf(fminf(bxp.z, gbox[n][2]) - fmaxf(bxp.x, gbox[n][0]), 0.0f);
                float iy = fmaxf(fminf(bxp.w, gbox[n][3]) - fmaxf(bxp.y, gbox[n][1]), 0.0f);
                float inter = ix * iy;
                float ag = (gbox[n][2] - gbox[n][0]) * (gbox[n][3] - gbox[n][1]);
                float un = fmaxf(ap2 + ag - inter, 1e-6f);
                best = fmaxf(best, inter / un);
            }
        }
        #pragma unroll
        for (int off = 32; off; off >>= 1)
            best = fmaxf(best, __shfl_xor(best, off));
        if (lane == 0) P.out[IOU_OFF + m] = best;
    }
}

extern "C" void kernel_launch(void* const* d_in, const int* in_sizes, int n_in,
                              void* d_out, int out_size, void* d_ws, size_t ws_size,
                              hipStream_t stream) {
    char* ws = (char*)d_ws;
    KParams prm;
    prm.fmap   = (const float*)d_in[0];
    prm.props  = (const float*)d_in[1];
    prm.bbx    = (const float*)d_in[2];
    prm.W1     = (const float*)d_in[3];
    prm.b1v    = (const float*)d_in[4];
    prm.W2     = (const float*)d_in[5];
    prm.b2v    = (const float*)d_in[6];
    prm.Wc     = (const float*)d_in[7];
    prm.bc     = (const float*)d_in[8];
    prm.Wd     = (const float*)d_in[9];
    prm.bd     = (const float*)d_in[10];
    prm.pbid   = (const int*)d_in[11];
    prm.gbid   = (const int*)d_in[12];
    prm.out    = (float*)d_out;
    prm.W1t    = (unsigned short*)(ws + W1T_OFF);
    prm.W2t    = (unsigned short*)(ws + W2T_OFF);
    prm.Wht    = (unsigned short*)(ws + WHT_OFF);
    prm.allmax = (unsigned short*)(ws + AM_OFF);
    prm.cnt    = (unsigned*)(ws + CNT_OFF);

    hipMemsetAsync(ws + CNT_OFF, 0, sizeof(unsigned), stream);
    k_all<<<dim3(GRID), dim3(1024), 0, stream>>>(prm);
}

// Round 12
// 44.219 us; speedup vs baseline: 5.7190x; 5.7190x over previous
//
#include <hip/hip_runtime.h>
#include <math.h>

constexpr int B_ = 8, C_ = 1280, H_ = 7, W_ = 7;
constexpr int M_ = 2048, N_ = 128, HID = 256, NC = 21;
constexpr int DET_OFF = M_ * NC;          // 43008
constexpr int IOU_OFF = M_ * NC + M_ * 4; // 51200
constexpr int NRECT = 784;                // 28 y-intervals x 28 x-intervals

typedef __attribute__((ext_vector_type(8))) short bf16x8;
typedef __attribute__((ext_vector_type(8))) unsigned short u16x8;
typedef __attribute__((ext_vector_type(4))) float f32x4;

// ws layout (bytes)
constexpr size_t W1T_OFF = 0;                    // 1280*256*2 = 655360
constexpr size_t W2T_OFF = W1T_OFF + 655360;     // 256*256*2  = 131072
constexpr size_t WHT_OFF = W2T_OFF + 131072;     // 32*256*2   =  16384
constexpr size_t AM_OFF  = WHT_OFF + 16384;      // 8*784*1280*2 = 16056320

// k_aux grid partitions
constexpr int RECT_BLKS    = B_ * 40;   // (img, 32-ch group) = 320
constexpr int PREP_W1_BLKS = 160;       // 1280*256 / (256*8)
constexpr int PREP_W2_BLKS = 32;
constexpr int PREP_WH_BLKS = 4;
constexpr int AUX_BLKS = RECT_BLKS + PREP_W1_BLKS + PREP_W2_BLKS + PREP_WH_BLKS; // 516

__device__ __forceinline__ unsigned short f2bf(float f) {
    unsigned u = __builtin_bit_cast(unsigned, f);
    u += 0x7FFFu + ((u >> 16) & 1u);   // round-to-nearest-even
    return (unsigned short)(u >> 16);
}
__device__ __forceinline__ float bf2f(unsigned short u) {
    return __builtin_bit_cast(float, (unsigned)u << 16);
}
// interval index for 0 <= s < e <= 7  ->  [0,28)
__device__ __forceinline__ int ivix(int s, int e) {
    return s * 7 - ((s * (s - 1)) >> 1) + (e - s - 1);
}

// ---------- k_aux: rect-max precompute + weight prep ----------
__global__ __launch_bounds__(256) void k_aux(
    const float* __restrict__ fmap,
    const float* __restrict__ W1, const float* __restrict__ W2,
    const float* __restrict__ Wc, const float* __restrict__ Wd,
    unsigned short* __restrict__ allmax, unsigned short* __restrict__ W1t,
    unsigned short* __restrict__ W2t,    unsigned short* __restrict__ Wht)
{
    __shared__ __align__(16) float tile[32 * 49];                 // 6.1 KB
    __shared__ __align__(16) unsigned short rect_lds[NRECT][36];  // 56.4 KB (pad 36)

    const int tid = threadIdx.x;
    const int b = blockIdx.x;

    if (b < RECT_BLKS) {
        int img = b / 40, c0 = (b % 40) * 32;
        const float* src = fmap + ((size_t)img * C_ + c0) * 49;
        for (int i4 = tid; i4 < 392; i4 += 256)
            *(float4*)&tile[i4 * 4] = *(const float4*)(src + i4 * 4);
        __syncthreads();

        int c = tid >> 3, sy = tid & 7;   // c in [0,32), sy in [0,8)
        if (sy < 7) {
            const float* tc = tile + c * 49;
            float colacc[7];
            #pragma unroll
            for (int x = 0; x < 7; ++x) colacc[x] = -INFINITY;
            for (int ey = sy + 1; ey <= 7; ++ey) {
                int y = ey - 1;
                #pragma unroll
                for (int x = 0; x < 7; ++x)
                    colacc[x] = fmaxf(colacc[x], tc[y * 7 + x]);
                int yi = ivix(sy, ey);
                int xi = 0;
                #pragma unroll
                for (int sx = 0; sx < 7; ++sx) {
                    float mx = -INFINITY;
                    #pragma unroll
                    for (int ex = sx + 1; ex <= 7; ++ex) {
                        mx = fmaxf(mx, colacc[ex - 1]);
                        rect_lds[yi * 28 + xi][c] = f2bf(mx);
                        ++xi;
                    }
                }
            }
        }
        __syncthreads();

        // writeback: 784 rects x 32 ch -> [img][rect][C]
        unsigned short* dst = allmax + (size_t)img * NRECT * C_ + c0;
        for (int i = tid; i < NRECT * 4; i += 256) {
            int rid = i >> 2, ch = (i & 3) * 8;
            ushort4 lo = *(const ushort4*)&rect_lds[rid][ch];
            ushort4 hi = *(const ushort4*)&rect_lds[rid][ch + 4];
            unsigned short* dp = dst + (size_t)rid * C_ + ch;
            *(ushort4*)dp = lo;
            *(ushort4*)(dp + 4) = hi;
        }
    } else if (b < RECT_BLKS + PREP_W1_BLKS) {
        int k0 = (b - RECT_BLKS) * 8;
        int col = tid;
        u16x8 o;
        #pragma unroll
        for (int j = 0; j < 8; ++j) o[j] = f2bf(W1[(size_t)(k0 + j) * HID + col]);
        *(u16x8*)(W1t + (size_t)col * C_ + k0) = o;
    } else if (b < RECT_BLKS + PREP_W1_BLKS + PREP_W2_BLKS) {
        int k0 = (b - RECT_BLKS - PREP_W1_BLKS) * 8;
        int col = tid;
        u16x8 o;
        #pragma unroll
        for (int j = 0; j < 8; ++j) o[j] = f2bf(W2[(size_t)(k0 + j) * HID + col]);
        *(u16x8*)(W2t + (size_t)col * HID + k0) = o;
    } else {
        int i = (b - RECT_BLKS - PREP_W1_BLKS - PREP_W2_BLKS) * 256 + tid;
        int o32 = i & 31;
        int k0  = (i >> 5) * 8;
        u16x8 o;
        #pragma unroll
        for (int j = 0; j < 8; ++j) {
            float v = 0.0f;
            if (o32 < NC) v = Wc[(size_t)(k0 + j) * NC + o32];
            else if (o32 < NC + 4) v = Wd[(size_t)(k0 + j) * 4 + (o32 - NC)];
            o[j] = f2bf(v);
        }
        *(u16x8*)(Wht + (size_t)o32 * HID + k0) = o;
    }
}

// ---------- k_fc: gather-pool -> FC1 -> FC2 -> heads + IoU; 8 proposals, 16 waves ----------
__global__ __launch_bounds__(1024) void k_fc(
    const unsigned short* __restrict__ allmax,
    const unsigned short* __restrict__ W1t,
    const unsigned short* __restrict__ W2t,
    const unsigned short* __restrict__ Wht,
    const float* __restrict__ b1v, const float* __restrict__ b2v,
    const float* __restrict__ bc,  const float* __restrict__ bd,
    const float* __restrict__ props, const int* __restrict__ pbid,
    const float* __restrict__ bbx,   const int* __restrict__ gbid,
    float* __restrict__ out)
{
    __shared__ unsigned short featL[8][1288];   // 20.6 KB
    __shared__ unsigned short h1s[16][264];
    __shared__ unsigned short h2s[16][264];
    __shared__ float gbox[N_][4];
    __shared__ int   gids[N_];

    const int tid = threadIdx.x;
    const int row0 = blockIdx.x * 8;

    if (tid < N_) {
        gbox[tid][0] = bbx[tid * 5 + 0];
        gbox[tid][1] = bbx[tid * 5 + 1];
        gbox[tid][2] = bbx[tid * 5 + 2];
        gbox[tid][3] = bbx[tid * 5 + 3];
        gids[tid] = gbid[tid];
    }

    // ---- gather-pool on first 8 waves: wave = proposal ----
    if (tid < 512) {
        int p = tid >> 6, lane = tid & 63;
        int m = row0 + p;
        float4 bx = *(const float4*)(props + (size_t)m * 4);
        float x1 = rintf(bx.x), y1 = rintf(bx.y);
        float x2 = rintf(bx.z), y2 = rintf(bx.w);
        float rw = fmaxf(x2 - x1 + 1.0f, 1.0f);
        float rh = fmaxf(y2 - y1 + 1.0f, 1.0f);
        float bw = rw * 0.5f, bh = rh * 0.5f;
        int hs0 = __builtin_amdgcn_readfirstlane((int)fminf(fmaxf(y1, 0.f), 7.f));
        int he0 = __builtin_amdgcn_readfirstlane((int)fminf(fmaxf(ceilf(bh) + y1, 0.f), 7.f));
        int hs1 = __builtin_amdgcn_readfirstlane((int)fminf(fmaxf(floorf(bh) + y1, 0.f), 7.f));
        int he1 = __builtin_amdgcn_readfirstlane((int)fminf(fmaxf(ceilf(2.f * bh) + y1, 0.f), 7.f));
        int ws0 = __builtin_amdgcn_readfirstlane((int)fminf(fmaxf(x1, 0.f), 7.f));
        int we0 = __builtin_amdgcn_readfirstlane((int)fminf(fmaxf(ceilf(bw) + x1, 0.f), 7.f));
        int ws1 = __builtin_amdgcn_readfirstlane((int)fminf(fmaxf(floorf(bw) + x1, 0.f), 7.f));
        int we1 = __builtin_amdgcn_readfirstlane((int)fminf(fmaxf(ceilf(2.f * bw) + x1, 0.f), 7.f));
        int bid = __builtin_amdgcn_readfirstlane(pbid[m]);

        int v00 = (he0 > hs0) & (we0 > ws0);
        int v01 = (he0 > hs0) & (we1 > ws1);
        int v10 = (he1 > hs1) & (we0 > ws0);
        int v11 = (he1 > hs1) & (we1 > ws1);
        int yi0 = v00 | v01 ? ivix(hs0, max(he0, hs0 + 1)) : 0;
        int yi1 = v10 | v11 ? ivix(hs1, max(he1, hs1 + 1)) : 0;
        int xi0 = v00 | v10 ? ivix(ws0, max(we0, ws0 + 1)) : 0;
        int xi1 = v01 | v11 ? ivix(ws1, max(we1, ws1 + 1)) : 0;
        const unsigned short* base = allmax + (size_t)bid * NRECT * C_;
        const unsigned short* a00 = base + (size_t)(yi0 * 28 + xi0) * C_;
        const unsigned short* a01 = base + (size_t)(yi0 * 28 + xi1) * C_;
        const unsigned short* a10 = base + (size_t)(yi1 * 28 + xi0) * C_;
        const unsigned short* a11 = base + (size_t)(yi1 * 28 + xi1) * C_;
        float m00 = v00 ? 0.25f : 0.0f;
        float m01 = v01 ? 0.25f : 0.0f;
        float m10 = v10 ? 0.25f : 0.0f;
        float m11 = v11 ? 0.25f : 0.0f;

        #pragma unroll
        for (int it = 0; it < 5; ++it) {
            int c = it * 256 + lane * 4;
            ushort4 u0 = *(const ushort4*)(a00 + c);
            ushort4 u1 = *(const ushort4*)(a01 + c);
            ushort4 u2 = *(const ushort4*)(a10 + c);
            ushort4 u3 = *(const ushort4*)(a11 + c);
            ushort4 o;
            o.x = f2bf(bf2f(u0.x) * m00 + bf2f(u1.x) * m01 + bf2f(u2.x) * m10 + bf2f(u3.x) * m11);
            o.y = f2bf(bf2f(u0.y) * m00 + bf2f(u1.y) * m01 + bf2f(u2.y) * m10 + bf2f(u3.y) * m11);
            o.z = f2bf(bf2f(u0.z) * m00 + bf2f(u1.z) * m01 + bf2f(u2.z) * m10 + bf2f(u3.z) * m11);
            o.w = f2bf(bf2f(u0.w) * m00 + bf2f(u1.w) * m01 + bf2f(u2.w) * m10 + bf2f(u3.w) * m11);
            *(ushort4*)&featL[p][c] = o;
        }
    }
    __syncthreads();

    const int w = tid >> 6, lane = tid & 63;
    const int r = lane & 15, g = lane >> 4;
    const int col0 = w * 16;                  // wave covers 16 cols

    // ---- FC1: A from LDS, B depth-4 register prefetch ----
    f32x4 acc = (f32x4){0.f, 0.f, 0.f, 0.f};
    const unsigned short* arp = featL[r & 7] + g * 8;
    const unsigned short* bp  = W1t + (size_t)(col0 + r) * C_ + g * 8;

    bf16x8 af[4], bf[4];
    #pragma unroll
    for (int i = 0; i < 4; ++i) {
        af[i] = *(const bf16x8*)(arp + i * 32);
        bf[i] = *(const bf16x8*)(bp  + i * 32);
    }
    #pragma unroll
    for (int ks = 4; ks < 40; ++ks) {
        int sl = ks & 3;
        acc = __builtin_amdgcn_mfma_f32_16x16x32_bf16(af[sl], bf[sl], acc, 0, 0, 0);
        af[sl] = *(const bf16x8*)(arp + ks * 32);
        bf[sl] = *(const bf16x8*)(bp  + ks * 32);
    }
    #pragma unroll
    for (int ks = 40; ks < 44; ++ks)
        acc = __builtin_amdgcn_mfma_f32_16x16x32_bf16(af[ks & 3], bf[ks & 3], acc, 0, 0, 0);

    {
        int col = col0 + r;
        float bias = b1v[col];
        #pragma unroll
        for (int i = 0; i < 4; ++i)
            h1s[g * 4 + i][col] = f2bf(fmaxf(acc[i] + bias, 0.f));
    }

    // ---- FC2 B preload (independent of h1s) BEFORE barrier ----
    const unsigned short* bq = W2t + (size_t)(col0 + r) * HID + g * 8;
    bf16x8 u[8];
    #pragma unroll
    for (int ks = 0; ks < 8; ++ks) u[ks] = *(const bf16x8*)(bq + ks * 32);

    __syncthreads();

    // ---- FC2: A from LDS, B preloaded ----
    f32x4 c2 = (f32x4){0.f, 0.f, 0.f, 0.f};
    #pragma unroll
    for (int ks = 0; ks < 8; ++ks) {
        bf16x8 a = *(const bf16x8*)(&h1s[r][ks * 32 + g * 8]);
        c2 = __builtin_amdgcn_mfma_f32_16x16x32_bf16(a, u[ks], c2, 0, 0, 0);
    }
    {
        int col = col0 + r;
        float bias = b2v[col];
        #pragma unroll
        for (int i = 0; i < 4; ++i)
            h2s[g * 4 + i][col] = f2bf(c2[i] + bias);
    }
    __syncthreads();

    // ---- heads on wave 0 (rows 0..7 valid) ----
    if (w == 0) {
        f32x4 acc3[2];
        #pragma unroll
        for (int f = 0; f < 2; ++f) acc3[f] = (f32x4){0.f, 0.f, 0.f, 0.f};
        const unsigned short* bp3 = Wht + (size_t)r * HID + g * 8;
        #pragma unroll
        for (int ks = 0; ks < 8; ++ks) {
            bf16x8 a = *(const bf16x8*)(&h2s[r][ks * 32 + g * 8]);
            #pragma unroll
            for (int f = 0; f < 2; ++f) {
                bf16x8 b = *(const bf16x8*)(bp3 + (size_t)f * 16 * HID + ks * 32);
                acc3[f] = __builtin_amdgcn_mfma_f32_16x16x32_bf16(a, b, acc3[f], 0, 0, 0);
            }
        }
        if (g < 2) {
            #pragma unroll
            for (int f = 0; f < 2; ++f) {
                int col = f * 16 + r;
                #pragma unroll
                for (int i = 0; i < 4; ++i) {
                    int m = row0 + g * 4 + i;
                    if (col < NC)
                        out[(size_t)m * NC + col] = acc3[f][i] + bc[col];
                    else if (col < NC + 4)
                        out[DET_OFF + (size_t)m * 4 + (col - NC)] = acc3[f][i] + bd[col - NC];
                }
            }
        }
    }

    // ---- IoU: waves 0..7, wave w handles proposal row0+w ----
    if (w < 8) {
        int m = row0 + w;
        float4 bxp = *(const float4*)(props + (size_t)m * 4);
        float ap2 = (bxp.z - bxp.x) * (bxp.w - bxp.y);
        int pb = pbid[m];
        float best = 0.0f;
        for (int n = lane; n < N_; n += 64) {
            if (gids[n] == pb) {
                float ix = fmaxf(fminf(bxp.z, gbox[n][2]) - fmaxf(bxp.x, gbox[n][0]), 0.0f);
                float iy = fmaxf(fminf(bxp.w, gbox[n][3]) - fmaxf(bxp.y, gbox[n][1]), 0.0f);
                float inter = ix * iy;
                float ag = (gbox[n][2] - gbox[n][0]) * (gbox[n][3] - gbox[n][1]);
                float un = fmaxf(ap2 + ag - inter, 1e-6f);
                best = fmaxf(best, inter / un);
            }
        }
        #pragma unroll
        for (int off = 32; off; off >>= 1)
            best = fmaxf(best, __shfl_xor(best, off));
        if (lane == 0) out[IOU_OFF + m] = best;
    }
}

extern "C" void kernel_launch(void* const* d_in, const int* in_sizes, int n_in,
                              void* d_out, int out_size, void* d_ws, size_t ws_size,
                              hipStream_t stream) {
    const float* fmap  = (const float*)d_in[0];
    const float* props = (const float*)d_in[1];
    const float* bbx   = (const float*)d_in[2];
    const float* W1    = (const float*)d_in[3];
    const float* b1v   = (const float*)d_in[4];
    const float* W2    = (const float*)d_in[5];
    const float* b2v   = (const float*)d_in[6];
    const float* Wc    = (const float*)d_in[7];
    const float* bc    = (const float*)d_in[8];
    const float* Wd    = (const float*)d_in[9];
    const float* bd    = (const float*)d_in[10];
    const int*   pbid  = (const int*)d_in[11];
    const int*   gbid  = (const int*)d_in[12];
    float* out = (float*)d_out;

    char* ws = (char*)d_ws;
    unsigned short* W1t    = (unsigned short*)(ws + W1T_OFF);
    unsigned short* W2t    = (unsigned short*)(ws + W2T_OFF);
    unsigned short* Wht    = (unsigned short*)(ws + WHT_OFF);
    unsigned short* allmax = (unsigned short*)(ws + AM_OFF);

    k_aux<<<dim3(AUX_BLKS), dim3(256), 0, stream>>>(
        fmap, W1, W2, Wc, Wd, allmax, W1t, W2t, Wht);
    k_fc<<<dim3(M_ / 8), dim3(1024), 0, stream>>>(
        allmax, W1t, W2t, Wht, b1v, b2v, bc, bd, props, pbid, bbx, gbid, out);
}